// Round 6
// baseline (331.738 us; speedup 1.0000x reference)
//
#include <hip/hip_runtime.h>

typedef float floatx4 __attribute__((ext_vector_type(4)));
typedef __bf16 bf16t;
typedef __bf16 bf16x8 __attribute__((ext_vector_type(8)));
typedef __bf16 bf16x4 __attribute__((ext_vector_type(4)));
typedef unsigned short u16t;
typedef unsigned int u32t;

// HW convert (RNE on gfx950)
static __device__ __forceinline__ u16t f2bf(float f) {
  return __builtin_bit_cast(u16t, (__bf16)f);
}
static __device__ __forceinline__ float bf2f(u16t h) {
  return __uint_as_float((u32t)h << 16);
}

#define MFMA(A, B, C) __builtin_amdgcn_mfma_f32_16x16x32_bf16((A), (B), (C), 0, 0, 0)

// Pre-pack w_qkv [128][384] and w_out [128][128] (fp32 row-major) into bf16.
// w_qkv: standard MFMA frag order: [(ntile*4+kstep)*64+lane]*8+j =
//   W[32*kstep + (lane>>4)*8 + j][16*ntile + (lane&15)]
// w_out: PERMUTED k-dim (pi): slot j carries row
//   32*kstep + 16*(j>>2) + 4*(lane>>4) + (j&3)
// matching the in-register attn fragment layout (swapped-PV C output), so the
// out-projection needs no LDS transpose of attn.
__global__ void pack_weights_kernel(const float* __restrict__ wqkv,
                                    const float* __restrict__ wout,
                                    u16t* __restrict__ wq_p,
                                    u16t* __restrict__ wo_p) {
  int g = blockIdx.x * blockDim.x + threadIdx.x;  // 0..8191
  int l = g & 63;
  int s = (g >> 6) & 3;
  int n = g >> 8;  // 0..31 : 0..23 -> w_qkv ntiles, 24..31 -> w_out ntiles
  int cl = l & 15;
  if (n < 24) {
    int kbase = 32 * s + ((l >> 4) * 8);
    int col = 16 * n + cl;
    u16t* dst = wq_p + g * 8;
#pragma unroll
    for (int j = 0; j < 8; ++j) dst[j] = f2bf(wqkv[(kbase + j) * 384 + col]);
  } else {
    int col = 16 * (n - 24) + cl;
    u16t* dst = wo_p + (g - 24 * 256) * 8;
    int rbase = 32 * s + 4 * (l >> 4);
#pragma unroll
    for (int j = 0; j < 8; ++j)
      dst[j] = f2bf(wout[(rbase + 16 * (j >> 2) + (j & 3)) * 128 + col]);
  }
}

// One workgroup per window (4096 windows). 256 threads = 4 waves.
// Wave w owns query tokens 16w..16w+15 through the whole pipe.
// Phase B is fully LDS-round-trip-free:
//  - Q projection output (swapped C: lane = q-chs 4lhi..+3, token llo) feeds
//    the score MFMA DIRECTLY from registers via a re-permuted k-dim:
//    k-slot (lhi,j) <-> (part=j>>2, ch=4lhi+(j&3)). B-frag = [q_hi|q_lo].
//  - K-side matches with a b64 read duplicated into both halves: start banks
//    (4llo+2lhi) mod 32 -> conflict-free (b128 version was 2x conflicted).
//  - P, attn stay in registers (swapped-PV + pi-packed w_out, as before).
//  - no manual fences: kb/v prefetches are compiler-counted lgkmcnt waits;
//    xnK/xv are read-only during Phase B.
// LDS: xnK 17408 + xv 18432 = 35840 B -> 4 blocks/CU.
__global__ __launch_bounds__(256, 4) void win_attn_kernel(
    const float* __restrict__ x, const float* __restrict__ gamma,
    const float* __restrict__ beta, const u16t* __restrict__ wq_p,
    const float* __restrict__ bqkv, const u16t* __restrict__ wo_p,
    const float* __restrict__ bout, float* __restrict__ out) {
  __shared__ u16t xnK[64][136];  // x_hi (LN) -> K all heads [token][ch]
  __shared__ u16t xv[9216];      // union: x_lo [64][136] -> V^T [128][72]

  const int tid = threadIdx.x;
  const int lane = tid & 63;
  const int w = tid >> 6;       // wave id = query tile
  const int llo = lane & 15;
  const int lhi = lane >> 4;

  const int wi = blockIdx.x;
  const int bimg = wi >> 6;
  const int widx = wi & 63;
  const int nwh = widx >> 3;
  const int nww = widx & 7;
  const int base_off = (((bimg * 56) + nwh * 7) * 56 + nww * 7) * 128;
  const float* xbase = x + base_off;

  // zero pad rows (tokens 49..63) of x_hi and x_lo
  for (int i = tid; i < 15 * 64; i += 256) {
    int r = 49 + (i >> 6), c = (i & 63) << 1;
    *(u32t*)&xnK[r][c] = 0;
    *(u32t*)&xv[r * 136 + c] = 0;
  }

  // ---- LayerNorm -> split bf16: hi in xnK, lo in xv. One wave per token ----
  {
    const float g0 = gamma[2 * lane], g1 = gamma[2 * lane + 1];
    const float b0 = beta[2 * lane], b1 = beta[2 * lane + 1];
    for (int t = w; t < 49; t += 4) {
      int wr = t / 7, wc = t - wr * 7;
      const float* row = xbase + (wr * 56 + wc) * 128;
      float2 v = *(const float2*)(row + 2 * lane);
      float sm = v.x + v.y;
      float sq = v.x * v.x + v.y * v.y;
#pragma unroll
      for (int m = 1; m < 64; m <<= 1) {
        sm += __shfl_xor(sm, m);
        sq += __shfl_xor(sq, m);
      }
      float mean = sm * (1.f / 128.f);
      float var = sq * (1.f / 128.f) - mean * mean;
      float rs = rsqrtf(var + 1e-5f);
      float y0 = (v.x - mean) * rs * g0 + b0;
      float y1 = (v.y - mean) * rs * g1 + b1;
      u16t h0 = f2bf(y0), h1 = f2bf(y1);
      u16t l0 = f2bf(y0 - bf2f(h0)), l1 = f2bf(y1 - bf2f(h1));
      *(u32t*)&xnK[t][2 * lane] = (u32t)h0 | ((u32t)h1 << 16);
      *(u32t*)&xv[t * 136 + 2 * lane] = (u32t)l0 | ((u32t)l1 << 16);
    }
  }
  __syncthreads();  // barrier 1: LN complete

  const int rowA = 16 * w + llo;      // A/B-frag row (token 16w + llo)
  const int rowC = 16 * w + lhi * 4;  // C-frag row base (non-swapped outputs)
  const floatx4 z4 = {0.f, 0.f, 0.f, 0.f};

  // ---- hoist loop-invariant x-fragments (this wave's 16 rows) ----
  bf16x8 a_hi[4], a_lo[4];
#pragma unroll
  for (int s = 0; s < 4; ++s) {
    a_hi[s] = *(const bf16x8*)&xnK[rowA][s * 32 + lhi * 8];
    a_lo[s] = *(const bf16x8*)&xv[rowA * 136 + s * 32 + lhi * 8];
  }
  // Q(0) weights (global; used after Phase A)
  bf16x8 bqw[4];
#pragma unroll
  for (int s = 0; s < 4; ++s)
    bqw[s] = *(const bf16x8*)(wq_p + (s * 64 + lane) * 8);
  __syncthreads();  // barrier 2: x_hi/x_lo consumed; regions become K / V^T

  // ---- Phase A: K (swapped, into xnK) and V^T (into xv) for ALL heads ----
#pragma unroll 2
  for (int h = 0; h < 8; ++h) {
    const u16t* pwk = wq_p + (((8 + h) * 4) * 64 + lane) * 8;
    const u16t* pwv = wq_p + (((16 + h) * 4) * 64 + lane) * 8;
    floatx4 ak = z4, av = z4;
#pragma unroll
    for (int s = 0; s < 4; ++s) {
      bf16x8 bk = *(const bf16x8*)(pwk + s * 512);
      bf16x8 bv = *(const bf16x8*)(pwv + s * 512);
      ak = MFMA(bk, a_hi[s], ak);  // swapped: lane = k-chs 4lhi..+3, tok llo
      ak = MFMA(bk, a_lo[s], ak);
      av = MFMA(a_hi[s], bv, av);  // normal:  lane = tok rowC..+3, ch llo
      av = MFMA(a_lo[s], bv, av);
    }
    // K store: K[token 16w+llo][ch h*16+4lhi .. +3] as one b64
    float4 bk4 = *(const float4*)(bqkv + 128 + h * 16 + 4 * lhi);
    ushort4 kk;
    kk.x = f2bf(ak[0] + bk4.x);
    kk.y = f2bf(ak[1] + bk4.y);
    kk.z = f2bf(ak[2] + bk4.z);
    kk.w = f2bf(ak[3] + bk4.w);
    *(ushort4*)&xnK[16 * w + llo][h * 16 + 4 * lhi] = kk;
    float bv_ = bqkv[256 + h * 16 + llo];
    ushort4 vv;
    vv.x = f2bf(av[0] + bv_);
    vv.y = f2bf(av[1] + bv_);
    vv.z = f2bf(av[2] + bv_);
    vv.w = f2bf(av[3] + bv_);
    *(ushort4*)&xv[(h * 16 + llo) * 72 + rowC] = vv;  // V^T[ch][token]
  }

  // ---- Q(0) in registers: B-frag [q_hi 4lhi+0..3 | q_lo 4lhi+0..3] ----
  bf16x8 qf;
  {
    floatx4 aq = z4;
#pragma unroll
    for (int s = 0; s < 4; ++s) aq = MFMA(bqw[s], a_hi[s], aq);
    float4 bq4 = *(const float4*)(bqkv + 4 * lhi);
    float q0 = aq[0] + bq4.x, q1 = aq[1] + bq4.y;
    float q2 = aq[2] + bq4.z, q3 = aq[3] + bq4.w;
    qf[0] = (bf16t)q0; qf[1] = (bf16t)q1;
    qf[2] = (bf16t)q2; qf[3] = (bf16t)q3;
    qf[4] = (bf16t)(q0 - (float)qf[0]);
    qf[5] = (bf16t)(q1 - (float)qf[1]);
    qf[6] = (bf16t)(q2 - (float)qf[2]);
    qf[7] = (bf16t)(q3 - (float)qf[3]);
  }
  __syncthreads();  // barrier 3 (last): K/V visible to all waves

  // K/V fragments for head 0 (b64 each; conflict-free bank pattern)
  bf16x4 kv4[4];
  bf16x4 v00, v01, v10, v11;
  {
#pragma unroll
    for (int n = 0; n < 4; ++n)
      kv4[n] = *(const bf16x4*)&xnK[16 * n + llo][4 * lhi];
    const int vrow = llo * 72;
    v00 = *(const bf16x4*)&xv[vrow + 4 * lhi];
    v01 = *(const bf16x4*)&xv[vrow + 16 + 4 * lhi];
    v10 = *(const bf16x4*)&xv[vrow + 32 + 4 * lhi];
    v11 = *(const bf16x4*)&xv[vrow + 48 + 4 * lhi];
  }

  // ---- Phase B: per-head attention, all-register P/Q/attn, fence-free ----
  const float SEXP = 0.25f * 1.44269504088896340736f;  // SCALE * log2(e)
  floatx4 oc[8];
#pragma unroll
  for (int n = 0; n < 8; ++n) oc[n] = z4;

#pragma unroll 1
  for (int p4 = 0; p4 < 4; ++p4) {
    bf16x8 atf;
#pragma unroll
    for (int hp = 0; hp < 2; ++hp) {
      const int h = 2 * p4 + hp;
      // 1. issue Q(h+1) weight loads (global; consumed at step 6)
      if (h < 7) {
        const u16t* pq = wq_p + (((h + 1) * 4) * 64 + lane) * 8;
#pragma unroll
        for (int s = 0; s < 4; ++s) bqw[s] = *(const bf16x8*)(pq + s * 512);
      }

      // 2. scores: sc[n] = K-tile(n) x Q; k-slot (lhi,j)=(part j>>2, ch
      //    4lhi+(j&3)); K duplicated across both halves (hi-only K)
      floatx4 sc[4];
#pragma unroll
      for (int n = 0; n < 4; ++n) {
        bf16x8 kbf =
            __builtin_shufflevector(kv4[n], kv4[n], 0, 1, 2, 3, 0, 1, 2, 3);
        sc[n] = MFMA(kbf, qf, z4);
      }

      // 3. prefetch next head's K/V fragments (no aliasing; counted waits)
      bf16x4 nk[4], nv0, nv1, nv2, nv3;
      if (h < 7) {
        const int kcol = (h + 1) * 16 + 4 * lhi;
#pragma unroll
        for (int n = 0; n < 4; ++n)
          nk[n] = *(const bf16x4*)&xnK[16 * n + llo][kcol];
        const int vrow = ((h + 1) * 16 + llo) * 72;
        nv0 = *(const bf16x4*)&xv[vrow + 4 * lhi];
        nv1 = *(const bf16x4*)&xv[vrow + 16 + 4 * lhi];
        nv2 = *(const bf16x4*)&xv[vrow + 32 + 4 * lhi];
        nv3 = *(const bf16x4*)&xv[vrow + 48 + 4 * lhi];
      }

      // 4. softmax (no max-sub). key = 16n + 4lhi + j; only n=3 masked.
      float s0 = 0.f;
#pragma unroll
      for (int n = 0; n < 4; ++n) {
#pragma unroll
        for (int j = 0; j < 4; ++j) {
          float pe;
          if (n == 3)
            pe = (4 * lhi + j < 1) ? exp2f(sc[n][j] * SEXP) : 0.f;
          else
            pe = exp2f(sc[n][j] * SEXP);
          sc[n][j] = pe;
          s0 += pe;
        }
      }
      s0 += __shfl_xor(s0, 16);
      s0 += __shfl_xor(s0, 32);
      float rq = 1.f / s0;  // per-query normalization (deferred)

      // 5. P pack + PV (swapped, same key permutation on both sides)
      bf16x8 PB0, PB1;
#pragma unroll
      for (int j = 0; j < 4; ++j) {
        PB0[j] = (bf16t)sc[0][j];
        PB0[4 + j] = (bf16t)sc[1][j];
        PB1[j] = (bf16t)sc[2][j];
        PB1[4 + j] = (bf16t)sc[3][j];
      }
      bf16x8 V0 = __builtin_shufflevector(v00, v01, 0, 1, 2, 3, 4, 5, 6, 7);
      bf16x8 V1 = __builtin_shufflevector(v10, v11, 0, 1, 2, 3, 4, 5, 6, 7);
      floatx4 ao = MFMA(V0, PB0, z4);
      ao = MFMA(V1, PB1, ao);
      atf[4 * hp + 0] = (bf16t)(ao[0] * rq);
      atf[4 * hp + 1] = (bf16t)(ao[1] * rq);
      atf[4 * hp + 2] = (bf16t)(ao[2] * rq);
      atf[4 * hp + 3] = (bf16t)(ao[3] * rq);

      // 6. Q(h+1) from registers (bqw loaded at step 1, ~a full head ago)
      if (h < 7) {
        floatx4 aq = z4;
#pragma unroll
        for (int s = 0; s < 4; ++s) aq = MFMA(bqw[s], a_hi[s], aq);
        float4 bq4 = *(const float4*)(bqkv + (h + 1) * 16 + 4 * lhi);
        float q0 = aq[0] + bq4.x, q1 = aq[1] + bq4.y;
        float q2 = aq[2] + bq4.z, q3 = aq[3] + bq4.w;
        qf[0] = (bf16t)q0; qf[1] = (bf16t)q1;
        qf[2] = (bf16t)q2; qf[3] = (bf16t)q3;
        qf[4] = (bf16t)(q0 - (float)qf[0]);
        qf[5] = (bf16t)(q1 - (float)qf[1]);
        qf[6] = (bf16t)(q2 - (float)qf[2]);
        qf[7] = (bf16t)(q3 - (float)qf[3]);
        // rotate prefetched K/V into place
#pragma unroll
        for (int n = 0; n < 4; ++n) kv4[n] = nk[n];
        v00 = nv0; v01 = nv1; v10 = nv2; v11 = nv3;
      }
    }
    // pair out-proj from registers (w_out pack is pi-permuted to match atf)
#pragma unroll
    for (int n = 0; n < 8; ++n)
      oc[n] = MFMA(atf,
                   *(const bf16x8*)(wo_p + ((n * 4 + p4) * 64 + lane) * 8),
                   oc[n]);
  }

  // ---- bias + merge-store (pure register epilogue) ----
  float bo[8];
#pragma unroll
  for (int n = 0; n < 8; ++n) bo[n] = bout[16 * n + llo];
  float* obase = out + base_off;
#pragma unroll
  for (int r = 0; r < 4; ++r) {
    int t = rowC + r;
    if (t < 49) {
      int wr = t / 7, wc = t - wr * 7;
      float* orow = obase + (wr * 56 + wc) * 128;
#pragma unroll
      for (int n = 0; n < 8; ++n) orow[16 * n + llo] = oc[n][r] + bo[n];
    }
  }
}

extern "C" void kernel_launch(void* const* d_in, const int* in_sizes, int n_in,
                              void* d_out, int out_size, void* d_ws,
                              size_t ws_size, hipStream_t stream) {
  const float* x = (const float*)d_in[0];
  const float* ln_g = (const float*)d_in[1];
  const float* ln_b = (const float*)d_in[2];
  const float* w_qkv = (const float*)d_in[3];
  const float* b_qkv = (const float*)d_in[4];
  const float* w_out = (const float*)d_in[5];
  const float* b_out = (const float*)d_in[6];
  float* out = (float*)d_out;

  u16t* wq_p = (u16t*)d_ws;          // 24*4*64*8 = 49152 bf16 (96 KB)
  u16t* wo_p = wq_p + 24 * 256 * 8;  // 8*4*64*8 = 16384 bf16 (32 KB)

  hipLaunchKernelGGL(pack_weights_kernel, dim3(32), dim3(256), 0, stream,
                     w_qkv, w_out, wq_p, wo_p);
  hipLaunchKernelGGL(win_attn_kernel, dim3(4096), dim3(256), 0, stream, x,
                     ln_g, ln_b, wq_p, b_qkv, wo_p, b_out, out);
}

// Round 7
// 314.055 us; speedup vs baseline: 1.0563x; 1.0563x over previous
//
#include <hip/hip_runtime.h>

typedef float floatx4 __attribute__((ext_vector_type(4)));
typedef __bf16 bf16t;
typedef __bf16 bf16x8 __attribute__((ext_vector_type(8)));
typedef __bf16 bf16x4 __attribute__((ext_vector_type(4)));
typedef unsigned short u16t;
typedef unsigned int u32t;

// HW convert (RNE on gfx950)
static __device__ __forceinline__ u16t f2bf(float f) {
  return __builtin_bit_cast(u16t, (__bf16)f);
}
static __device__ __forceinline__ float bf2f(u16t h) {
  return __uint_as_float((u32t)h << 16);
}

#define MFMA(A, B, C) __builtin_amdgcn_mfma_f32_16x16x32_bf16((A), (B), (C), 0, 0, 0)

// Pre-pack w_qkv [128][384] and w_out [128][128] (fp32 row-major) into bf16.
// w_qkv: standard MFMA frag order: [(ntile*4+kstep)*64+lane]*8+j =
//   W[32*kstep + (lane>>4)*8 + j][16*ntile + (lane&15)]
// w_out: PERMUTED k-dim (pi): slot j carries row
//   32*kstep + 16*(j>>2) + 4*(lane>>4) + (j&3)
// matching the in-register attn fragment layout (swapped-PV C output), so the
// out-projection needs no LDS transpose of attn.
__global__ void pack_weights_kernel(const float* __restrict__ wqkv,
                                    const float* __restrict__ wout,
                                    u16t* __restrict__ wq_p,
                                    u16t* __restrict__ wo_p) {
  int g = blockIdx.x * blockDim.x + threadIdx.x;  // 0..8191
  int l = g & 63;
  int s = (g >> 6) & 3;
  int n = g >> 8;  // 0..31 : 0..23 -> w_qkv ntiles, 24..31 -> w_out ntiles
  int cl = l & 15;
  if (n < 24) {
    int kbase = 32 * s + ((l >> 4) * 8);
    int col = 16 * n + cl;
    u16t* dst = wq_p + g * 8;
#pragma unroll
    for (int j = 0; j < 8; ++j) dst[j] = f2bf(wqkv[(kbase + j) * 384 + col]);
  } else {
    int col = 16 * (n - 24) + cl;
    u16t* dst = wo_p + (g - 24 * 256) * 8;
    int rbase = 32 * s + 4 * (l >> 4);
#pragma unroll
    for (int j = 0; j < 8; ++j)
      dst[j] = f2bf(wout[(rbase + 16 * (j >> 2) + (j & 3)) * 128 + col]);
  }
}

// One workgroup per window (4096 windows). 256 threads = 4 waves.
// Wave w owns query tokens 16w..16w+15 through the whole pipe.
//  - Phase A computes K (swapped C -> b64 store), V^T, AND all 8 heads' Q
//    (swapped C kept in registers qall[8], split hi+lo; static indexing via
//    full unroll).
//  - Phase B per head: 4 score MFMAs (K b64 dup-read, conflict-free) +
//    softmax + 2 PV MFMAs. Zero LDS writes, zero fences, no weight loads.
//  - P/attn stay in registers (swapped-PV + pi-packed w_out).
//  - amdgpu_waves_per_eu(4,4): occupancy is LDS-bound at 4 blocks/CU, so let
//    the allocator use 128 VGPRs instead of spilling to chase 8 waves/EU
//    (R6's +58MB scratch-write regression).
// LDS: xnK 17408 + xv 18432 = 35840 B -> 4 blocks/CU.
__global__ __launch_bounds__(256)
__attribute__((amdgpu_waves_per_eu(4, 4))) void win_attn_kernel(
    const float* __restrict__ x, const float* __restrict__ gamma,
    const float* __restrict__ beta, const u16t* __restrict__ wq_p,
    const float* __restrict__ bqkv, const u16t* __restrict__ wo_p,
    const float* __restrict__ bout, float* __restrict__ out) {
  __shared__ u16t xnK[64][136];  // x_hi (LN) -> K all heads [token][ch]
  __shared__ u16t xv[9216];      // union: x_lo [64][136] -> V^T [128][72]

  const int tid = threadIdx.x;
  const int lane = tid & 63;
  const int w = tid >> 6;       // wave id = query tile
  const int llo = lane & 15;
  const int lhi = lane >> 4;

  const int wi = blockIdx.x;
  const int bimg = wi >> 6;
  const int widx = wi & 63;
  const int nwh = widx >> 3;
  const int nww = widx & 7;
  const int base_off = (((bimg * 56) + nwh * 7) * 56 + nww * 7) * 128;
  const float* xbase = x + base_off;

  // zero pad rows (tokens 49..63) of x_hi and x_lo
  for (int i = tid; i < 15 * 64; i += 256) {
    int r = 49 + (i >> 6), c = (i & 63) << 1;
    *(u32t*)&xnK[r][c] = 0;
    *(u32t*)&xv[r * 136 + c] = 0;
  }

  // ---- LayerNorm -> split bf16: hi in xnK, lo in xv. One wave per token ----
  {
    const float g0 = gamma[2 * lane], g1 = gamma[2 * lane + 1];
    const float b0 = beta[2 * lane], b1 = beta[2 * lane + 1];
    for (int t = w; t < 49; t += 4) {
      int wr = t / 7, wc = t - wr * 7;
      const float* row = xbase + (wr * 56 + wc) * 128;
      float2 v = *(const float2*)(row + 2 * lane);
      float sm = v.x + v.y;
      float sq = v.x * v.x + v.y * v.y;
#pragma unroll
      for (int m = 1; m < 64; m <<= 1) {
        sm += __shfl_xor(sm, m);
        sq += __shfl_xor(sq, m);
      }
      float mean = sm * (1.f / 128.f);
      float var = sq * (1.f / 128.f) - mean * mean;
      float rs = rsqrtf(var + 1e-5f);
      float y0 = (v.x - mean) * rs * g0 + b0;
      float y1 = (v.y - mean) * rs * g1 + b1;
      u16t h0 = f2bf(y0), h1 = f2bf(y1);
      u16t l0 = f2bf(y0 - bf2f(h0)), l1 = f2bf(y1 - bf2f(h1));
      *(u32t*)&xnK[t][2 * lane] = (u32t)h0 | ((u32t)h1 << 16);
      *(u32t*)&xv[t * 136 + 2 * lane] = (u32t)l0 | ((u32t)l1 << 16);
    }
  }
  __syncthreads();  // barrier 1: LN complete

  const int rowA = 16 * w + llo;      // A/B-frag row (token 16w + llo)
  const int rowC = 16 * w + lhi * 4;  // C-frag row base (non-swapped outputs)
  const floatx4 z4 = {0.f, 0.f, 0.f, 0.f};

  // ---- hoist loop-invariant x-fragments (this wave's 16 rows) ----
  bf16x8 a_hi[4], a_lo[4];
#pragma unroll
  for (int s = 0; s < 4; ++s) {
    a_hi[s] = *(const bf16x8*)&xnK[rowA][s * 32 + lhi * 8];
    a_lo[s] = *(const bf16x8*)&xv[rowA * 136 + s * 32 + lhi * 8];
  }
  __syncthreads();  // barrier 2: x_hi/x_lo consumed; regions become K / V^T

  // ---- Phase A1: K (swapped, into xnK) and V^T (into xv) for ALL heads ----
#pragma unroll 2
  for (int h = 0; h < 8; ++h) {
    const u16t* pwk = wq_p + (((8 + h) * 4) * 64 + lane) * 8;
    const u16t* pwv = wq_p + (((16 + h) * 4) * 64 + lane) * 8;
    floatx4 ak = z4, av = z4;
#pragma unroll
    for (int s = 0; s < 4; ++s) {
      bf16x8 bk = *(const bf16x8*)(pwk + s * 512);
      bf16x8 bv = *(const bf16x8*)(pwv + s * 512);
      ak = MFMA(bk, a_hi[s], ak);  // swapped: lane = k-chs 4lhi..+3, tok llo
      ak = MFMA(bk, a_lo[s], ak);
      av = MFMA(a_hi[s], bv, av);  // normal:  lane = tok rowC..+3, ch llo
      av = MFMA(a_lo[s], bv, av);
    }
    // K store: K[token 16w+llo][ch h*16+4lhi .. +3] as one b64
    float4 bk4 = *(const float4*)(bqkv + 128 + h * 16 + 4 * lhi);
    ushort4 kk;
    kk.x = f2bf(ak[0] + bk4.x);
    kk.y = f2bf(ak[1] + bk4.y);
    kk.z = f2bf(ak[2] + bk4.z);
    kk.w = f2bf(ak[3] + bk4.w);
    *(ushort4*)&xnK[16 * w + llo][h * 16 + 4 * lhi] = kk;
    float bv_ = bqkv[256 + h * 16 + llo];
    ushort4 vv;
    vv.x = f2bf(av[0] + bv_);
    vv.y = f2bf(av[1] + bv_);
    vv.z = f2bf(av[2] + bv_);
    vv.w = f2bf(av[3] + bv_);
    *(ushort4*)&xv[(h * 16 + llo) * 72 + rowC] = vv;  // V^T[ch][token]
  }

  // ---- Phase A2: ALL heads' Q in registers (swapped C; hi-only input) ----
  // qall[h] = B-frag [q_hi(4lhi..+3) | q_lo(4lhi..+3)] for token llo.
  bf16x8 qall[8];
#pragma unroll
  for (int h = 0; h < 8; ++h) {
    const u16t* pq = wq_p + ((h * 4) * 64 + lane) * 8;
    floatx4 aq = z4;
#pragma unroll
    for (int s = 0; s < 4; ++s)
      aq = MFMA(*(const bf16x8*)(pq + s * 512), a_hi[s], aq);
    float4 bq4 = *(const float4*)(bqkv + h * 16 + 4 * lhi);
    float q0 = aq[0] + bq4.x, q1 = aq[1] + bq4.y;
    float q2 = aq[2] + bq4.z, q3 = aq[3] + bq4.w;
    qall[h][0] = (bf16t)q0;
    qall[h][1] = (bf16t)q1;
    qall[h][2] = (bf16t)q2;
    qall[h][3] = (bf16t)q3;
    qall[h][4] = (bf16t)(q0 - (float)qall[h][0]);
    qall[h][5] = (bf16t)(q1 - (float)qall[h][1]);
    qall[h][6] = (bf16t)(q2 - (float)qall[h][2]);
    qall[h][7] = (bf16t)(q3 - (float)qall[h][3]);
  }
  __syncthreads();  // barrier 3 (last): K/V visible to all waves

  // K/V fragments for head 0 (b64 each; conflict-free bank pattern)
  bf16x4 kv4[4], vv4[4];
#pragma unroll
  for (int n = 0; n < 4; ++n)
    kv4[n] = *(const bf16x4*)&xnK[16 * n + llo][4 * lhi];
  {
    const int vrow = llo * 72;
#pragma unroll
    for (int i = 0; i < 4; ++i)
      vv4[i] = *(const bf16x4*)&xv[vrow + 16 * i + 4 * lhi];
  }

  // ---- Phase B: per-head attention, all-register, fence-free, unrolled ----
  const float SEXP = 0.25f * 1.44269504088896340736f;  // SCALE * log2(e)
  floatx4 oc[8];
#pragma unroll
  for (int n = 0; n < 8; ++n) oc[n] = z4;
  bf16x8 atf;

#pragma unroll
  for (int h = 0; h < 8; ++h) {
    // scores: sc[n] = K-tile(n) x Q; k-slot (lhi,j) = (part j>>2, ch
    // 4lhi+(j&3)); K duplicated across both halves (hi-only K)
    floatx4 sc[4];
#pragma unroll
    for (int n = 0; n < 4; ++n) {
      bf16x8 kbf =
          __builtin_shufflevector(kv4[n], kv4[n], 0, 1, 2, 3, 0, 1, 2, 3);
      sc[n] = MFMA(kbf, qall[h], z4);
    }
    // capture V frags for this head, then load next head's K/V
    bf16x8 V0 = __builtin_shufflevector(vv4[0], vv4[1], 0, 1, 2, 3, 4, 5, 6, 7);
    bf16x8 V1 = __builtin_shufflevector(vv4[2], vv4[3], 0, 1, 2, 3, 4, 5, 6, 7);
    if (h < 7) {
      const int kcol = (h + 1) * 16 + 4 * lhi;
#pragma unroll
      for (int n = 0; n < 4; ++n)
        kv4[n] = *(const bf16x4*)&xnK[16 * n + llo][kcol];
      const int vrow = ((h + 1) * 16 + llo) * 72;
#pragma unroll
      for (int i = 0; i < 4; ++i)
        vv4[i] = *(const bf16x4*)&xv[vrow + 16 * i + 4 * lhi];
    }

    // softmax (no max-sub). key = 16n + 4lhi + j; only n=3 masked.
    float s0 = 0.f;
#pragma unroll
    for (int n = 0; n < 4; ++n) {
#pragma unroll
      for (int j = 0; j < 4; ++j) {
        float pe;
        if (n == 3)
          pe = (4 * lhi + j < 1) ? exp2f(sc[n][j] * SEXP) : 0.f;
        else
          pe = exp2f(sc[n][j] * SEXP);
        sc[n][j] = pe;
        s0 += pe;
      }
    }
    s0 += __shfl_xor(s0, 16);
    s0 += __shfl_xor(s0, 32);
    float rq = 1.f / s0;  // per-query normalization (deferred)

    // P pack + PV (swapped, same key permutation on both sides)
    bf16x8 PB0, PB1;
#pragma unroll
    for (int j = 0; j < 4; ++j) {
      PB0[j] = (bf16t)sc[0][j];
      PB0[4 + j] = (bf16t)sc[1][j];
      PB1[j] = (bf16t)sc[2][j];
      PB1[4 + j] = (bf16t)sc[3][j];
    }
    floatx4 ao = MFMA(V0, PB0, z4);
    ao = MFMA(V1, PB1, ao);
    const int hp = h & 1;
    atf[4 * hp + 0] = (bf16t)(ao[0] * rq);
    atf[4 * hp + 1] = (bf16t)(ao[1] * rq);
    atf[4 * hp + 2] = (bf16t)(ao[2] * rq);
    atf[4 * hp + 3] = (bf16t)(ao[3] * rq);

    // pair out-proj from registers (w_out pack is pi-permuted to match atf)
    if (hp) {
      const int p4 = h >> 1;
#pragma unroll
      for (int n = 0; n < 8; ++n)
        oc[n] = MFMA(atf,
                     *(const bf16x8*)(wo_p + ((n * 4 + p4) * 64 + lane) * 8),
                     oc[n]);
    }
  }

  // ---- bias + merge-store (pure register epilogue) ----
  float bo[8];
#pragma unroll
  for (int n = 0; n < 8; ++n) bo[n] = bout[16 * n + llo];
  float* obase = out + base_off;
#pragma unroll
  for (int r = 0; r < 4; ++r) {
    int t = rowC + r;
    if (t < 49) {
      int wr = t / 7, wc = t - wr * 7;
      float* orow = obase + (wr * 56 + wc) * 128;
#pragma unroll
      for (int n = 0; n < 8; ++n) orow[16 * n + llo] = oc[n][r] + bo[n];
    }
  }
}

extern "C" void kernel_launch(void* const* d_in, const int* in_sizes, int n_in,
                              void* d_out, int out_size, void* d_ws,
                              size_t ws_size, hipStream_t stream) {
  const float* x = (const float*)d_in[0];
  const float* ln_g = (const float*)d_in[1];
  const float* ln_b = (const float*)d_in[2];
  const float* w_qkv = (const float*)d_in[3];
  const float* b_qkv = (const float*)d_in[4];
  const float* w_out = (const float*)d_in[5];
  const float* b_out = (const float*)d_in[6];
  float* out = (float*)d_out;

  u16t* wq_p = (u16t*)d_ws;          // 24*4*64*8 = 49152 bf16 (96 KB)
  u16t* wo_p = wq_p + 24 * 256 * 8;  // 8*4*64*8 = 16384 bf16 (32 KB)

  hipLaunchKernelGGL(pack_weights_kernel, dim3(32), dim3(256), 0, stream,
                     w_qkv, w_out, wq_p, wo_p);
  hipLaunchKernelGGL(win_attn_kernel, dim3(4096), dim3(256), 0, stream, x,
                     ln_g, ln_b, wq_p, b_qkv, wo_p, b_out, out);
}

// Round 9
// 313.619 us; speedup vs baseline: 1.0578x; 1.0014x over previous
//
#include <hip/hip_runtime.h>

typedef float floatx4 __attribute__((ext_vector_type(4)));
typedef __bf16 bf16t;
typedef __bf16 bf16x8 __attribute__((ext_vector_type(8)));
typedef __bf16 bf16x4 __attribute__((ext_vector_type(4)));
typedef unsigned short u16t;
typedef unsigned int u32t;

// HW convert (RNE on gfx950)
static __device__ __forceinline__ u16t f2bf(float f) {
  return __builtin_bit_cast(u16t, (__bf16)f);
}
static __device__ __forceinline__ float bf2f(u16t h) {
  return __uint_as_float((u32t)h << 16);
}

#define MFMA(A, B, C) __builtin_amdgcn_mfma_f32_16x16x32_bf16((A), (B), (C), 0, 0, 0)

// Pre-pack w_qkv [128][384] and w_out [128][128] (fp32 row-major) into bf16.
// w_qkv: standard MFMA frag order: [(ntile*4+kstep)*64+lane]*8+j =
//   W[32*kstep + (lane>>4)*8 + j][16*ntile + (lane&15)]
// w_out: PERMUTED k-dim (pi): slot j carries row
//   32*kstep + 16*(j>>2) + 4*(lane>>4) + (j&3)
// matching the in-register attn fragment layout (swapped-PV C output), so the
// out-projection needs no LDS transpose of attn.
__global__ void pack_weights_kernel(const float* __restrict__ wqkv,
                                    const float* __restrict__ wout,
                                    u16t* __restrict__ wq_p,
                                    u16t* __restrict__ wo_p) {
  int g = blockIdx.x * blockDim.x + threadIdx.x;  // 0..8191
  int l = g & 63;
  int s = (g >> 6) & 3;
  int n = g >> 8;  // 0..31 : 0..23 -> w_qkv ntiles, 24..31 -> w_out ntiles
  int cl = l & 15;
  if (n < 24) {
    int kbase = 32 * s + ((l >> 4) * 8);
    int col = 16 * n + cl;
    u16t* dst = wq_p + g * 8;
#pragma unroll
    for (int j = 0; j < 8; ++j) dst[j] = f2bf(wqkv[(kbase + j) * 384 + col]);
  } else {
    int col = 16 * (n - 24) + cl;
    u16t* dst = wo_p + (g - 24 * 256) * 8;
    int rbase = 32 * s + 4 * (l >> 4);
#pragma unroll
    for (int j = 0; j < 8; ++j)
      dst[j] = f2bf(wout[(rbase + 16 * (j >> 2) + (j & 3)) * 128 + col]);
  }
}

// One workgroup per window (4096 windows). 256 threads = 4 waves.
// Wave w owns query tokens 16w..16w+15 through the whole pipe.
// Register-budget-balanced version (fits the 64-VGPR allocation, no spill):
//  - qall[8] is Q hi-only (bf16x4, 2 regs/head); score MFMA uses [q|q] x [k|k]
//    = 2*(q.k), absorbed by halving SEXP.
//  - PV results accumulate in atf_all[4] (bf16, 16 regs); the out-projection
//    runs ONCE in the epilogue when qall/kv/vv/sc are dead. qall shrinks as
//    atf_all grows -> their sum stays ~18 regs through Phase B.
//  - scores streamed: sc_n (4 regs) -> exp -> PB pack, per tile n (no max-sub,
//    so exp needs no cross-tile reduction first). Same summation order.
//  - Phase B: zero LDS writes, zero fences; K b64 dup-reads conflict-free.
// LDS: xnK 17408 + xv 18432 = 35840 B -> 4 blocks/CU.
__global__ __launch_bounds__(256)
__attribute__((amdgpu_waves_per_eu(4, 4))) void win_attn_kernel(
    const float* __restrict__ x, const float* __restrict__ gamma,
    const float* __restrict__ beta, const u16t* __restrict__ wq_p,
    const float* __restrict__ bqkv, const u16t* __restrict__ wo_p,
    const float* __restrict__ bout, float* __restrict__ out) {
  __shared__ u16t xnK[64][136];  // x_hi (LN) -> K all heads [token][ch]
  __shared__ u16t xv[9216];      // union: x_lo [64][136] -> V^T [128][72]

  const int tid = threadIdx.x;
  const int lane = tid & 63;
  const int w = tid >> 6;       // wave id = query tile
  const int llo = lane & 15;
  const int lhi = lane >> 4;

  const int wi = blockIdx.x;
  const int bimg = wi >> 6;
  const int widx = wi & 63;
  const int nwh = widx >> 3;
  const int nww = widx & 7;
  const int base_off = (((bimg * 56) + nwh * 7) * 56 + nww * 7) * 128;
  const float* xbase = x + base_off;

  // zero pad rows (tokens 49..63) of x_hi and x_lo
  for (int i = tid; i < 15 * 64; i += 256) {
    int r = 49 + (i >> 6), c = (i & 63) << 1;
    *(u32t*)&xnK[r][c] = 0;
    *(u32t*)&xv[r * 136 + c] = 0;
  }

  // ---- LayerNorm -> split bf16: hi in xnK, lo in xv. One wave per token ----
  {
    const float g0 = gamma[2 * lane], g1 = gamma[2 * lane + 1];
    const float b0 = beta[2 * lane], b1 = beta[2 * lane + 1];
    for (int t = w; t < 49; t += 4) {
      int wr = t / 7, wc = t - wr * 7;
      const float* row = xbase + (wr * 56 + wc) * 128;
      float2 v = *(const float2*)(row + 2 * lane);
      float sm = v.x + v.y;
      float sq = v.x * v.x + v.y * v.y;
#pragma unroll
      for (int m = 1; m < 64; m <<= 1) {
        sm += __shfl_xor(sm, m);
        sq += __shfl_xor(sq, m);
      }
      float mean = sm * (1.f / 128.f);
      float var = sq * (1.f / 128.f) - mean * mean;
      float rs = rsqrtf(var + 1e-5f);
      float y0 = (v.x - mean) * rs * g0 + b0;
      float y1 = (v.y - mean) * rs * g1 + b1;
      u16t h0 = f2bf(y0), h1 = f2bf(y1);
      u16t l0 = f2bf(y0 - bf2f(h0)), l1 = f2bf(y1 - bf2f(h1));
      *(u32t*)&xnK[t][2 * lane] = (u32t)h0 | ((u32t)h1 << 16);
      *(u32t*)&xv[t * 136 + 2 * lane] = (u32t)l0 | ((u32t)l1 << 16);
    }
  }
  __syncthreads();  // barrier 1: LN complete

  const int rowA = 16 * w + llo;      // A/B-frag row (token 16w + llo)
  const int rowC = 16 * w + lhi * 4;  // C-frag row base (non-swapped outputs)
  const floatx4 z4 = {0.f, 0.f, 0.f, 0.f};

  // ---- hoist loop-invariant x-fragments (this wave's 16 rows) ----
  bf16x8 a_hi[4], a_lo[4];
#pragma unroll
  for (int s = 0; s < 4; ++s) {
    a_hi[s] = *(const bf16x8*)&xnK[rowA][s * 32 + lhi * 8];
    a_lo[s] = *(const bf16x8*)&xv[rowA * 136 + s * 32 + lhi * 8];
  }
  __syncthreads();  // barrier 2: x_hi/x_lo consumed; regions become K / V^T

  // ---- Phase A1: K (swapped, into xnK) and V^T (into xv) for ALL heads ----
#pragma unroll 2
  for (int h = 0; h < 8; ++h) {
    const u16t* pwk = wq_p + (((8 + h) * 4) * 64 + lane) * 8;
    const u16t* pwv = wq_p + (((16 + h) * 4) * 64 + lane) * 8;
    floatx4 ak = z4, av = z4;
#pragma unroll
    for (int s = 0; s < 4; ++s) {
      bf16x8 bk = *(const bf16x8*)(pwk + s * 512);
      bf16x8 bv = *(const bf16x8*)(pwv + s * 512);
      ak = MFMA(bk, a_hi[s], ak);  // swapped: lane = k-chs 4lhi..+3, tok llo
      ak = MFMA(bk, a_lo[s], ak);
      av = MFMA(a_hi[s], bv, av);  // normal:  lane = tok rowC..+3, ch llo
      av = MFMA(a_lo[s], bv, av);
    }
    // K store: K[token 16w+llo][ch h*16+4lhi .. +3] as one b64
    float4 bk4 = *(const float4*)(bqkv + 128 + h * 16 + 4 * lhi);
    ushort4 kk;
    kk.x = f2bf(ak[0] + bk4.x);
    kk.y = f2bf(ak[1] + bk4.y);
    kk.z = f2bf(ak[2] + bk4.z);
    kk.w = f2bf(ak[3] + bk4.w);
    *(ushort4*)&xnK[16 * w + llo][h * 16 + 4 * lhi] = kk;
    float bv_ = bqkv[256 + h * 16 + llo];
    ushort4 vv;
    vv.x = f2bf(av[0] + bv_);
    vv.y = f2bf(av[1] + bv_);
    vv.z = f2bf(av[2] + bv_);
    vv.w = f2bf(av[3] + bv_);
    *(ushort4*)&xv[(h * 16 + llo) * 72 + rowC] = vv;  // V^T[ch][token]
  }

  // ---- Phase A2: all heads' Q (hi-only, swapped C) in registers ----
  // qall[h] = bf16x4 of Q[token llo][ch h*16 + 4lhi .. +3]
  bf16x4 qall[8];
#pragma unroll
  for (int h = 0; h < 8; ++h) {
    const u16t* pq = wq_p + ((h * 4) * 64 + lane) * 8;
    floatx4 aq = z4;
#pragma unroll
    for (int s = 0; s < 4; ++s)
      aq = MFMA(*(const bf16x8*)(pq + s * 512), a_hi[s], aq);
    float4 bq4 = *(const float4*)(bqkv + h * 16 + 4 * lhi);
    qall[h][0] = (bf16t)(aq[0] + bq4.x);
    qall[h][1] = (bf16t)(aq[1] + bq4.y);
    qall[h][2] = (bf16t)(aq[2] + bq4.z);
    qall[h][3] = (bf16t)(aq[3] + bq4.w);
  }
  __syncthreads();  // barrier 3 (last): K/V visible to all waves

  // K/V fragments for head 0 (b64 each; conflict-free bank pattern)
  bf16x4 kv4[4], vv4[4];
#pragma unroll
  for (int n = 0; n < 4; ++n)
    kv4[n] = *(const bf16x4*)&xnK[16 * n + llo][4 * lhi];
  {
    const int vrow = llo * 72;
#pragma unroll
    for (int i = 0; i < 4; ++i)
      vv4[i] = *(const bf16x4*)&xv[vrow + 16 * i + 4 * lhi];
  }

  // ---- Phase B: per-head attention, all-register, fence-free, unrolled ----
  // SEXP includes the extra 0.5 from the [q|q] x [k|k] doubled k-dim.
  const float SEXP = 0.125f * 1.44269504088896340736f;  // 0.5*SCALE*log2(e)
  bf16x8 atf_all[4];

#pragma unroll
  for (int h = 0; h < 8; ++h) {
    bf16x8 qfh =
        __builtin_shufflevector(qall[h], qall[h], 0, 1, 2, 3, 0, 1, 2, 3);
    // streamed scores+exp: one tile n at a time (4 transient regs), pack PB
    float s0 = 0.f;
    bf16x8 PB0, PB1;
#pragma unroll
    for (int n = 0; n < 4; ++n) {
      bf16x8 kbf =
          __builtin_shufflevector(kv4[n], kv4[n], 0, 1, 2, 3, 0, 1, 2, 3);
      floatx4 scn = MFMA(kbf, qfh, z4);
#pragma unroll
      for (int j = 0; j < 4; ++j) {
        float pe;
        if (n == 3)
          pe = (4 * lhi + j < 1) ? exp2f(scn[j] * SEXP) : 0.f;
        else
          pe = exp2f(scn[j] * SEXP);
        if (n < 2)
          PB0[4 * n + j] = (bf16t)pe;
        else
          PB1[4 * (n - 2) + j] = (bf16t)pe;
        s0 += pe;
      }
    }
    // capture V frags for this head, then load next head's K/V
    bf16x8 V0 = __builtin_shufflevector(vv4[0], vv4[1], 0, 1, 2, 3, 4, 5, 6, 7);
    bf16x8 V1 = __builtin_shufflevector(vv4[2], vv4[3], 0, 1, 2, 3, 4, 5, 6, 7);
    if (h < 7) {
      const int kcol = (h + 1) * 16 + 4 * lhi;
#pragma unroll
      for (int n = 0; n < 4; ++n)
        kv4[n] = *(const bf16x4*)&xnK[16 * n + llo][kcol];
      const int vrow = ((h + 1) * 16 + llo) * 72;
#pragma unroll
      for (int i = 0; i < 4; ++i)
        vv4[i] = *(const bf16x4*)&xv[vrow + 16 * i + 4 * lhi];
    }

    s0 += __shfl_xor(s0, 16);
    s0 += __shfl_xor(s0, 32);
    float rq = 1.f / s0;  // per-query normalization (deferred)

    // PV (swapped, same key permutation both sides); stage into atf_all
    floatx4 ao = MFMA(V0, PB0, z4);
    ao = MFMA(V1, PB1, ao);
    const int hp = h & 1;
#pragma unroll
    for (int r = 0; r < 4; ++r)
      atf_all[h >> 1][4 * hp + r] = (bf16t)(ao[r] * rq);
  }

  // ---- epilogue: out-projection (qall/kv/vv/sc all dead -> regs free) ----
  floatx4 oc[8];
#pragma unroll
  for (int n = 0; n < 8; ++n) oc[n] = z4;
#pragma unroll
  for (int p4 = 0; p4 < 4; ++p4) {
#pragma unroll
    for (int n = 0; n < 8; ++n)
      oc[n] = MFMA(atf_all[p4],
                   *(const bf16x8*)(wo_p + ((n * 4 + p4) * 64 + lane) * 8),
                   oc[n]);
  }

  // ---- bias + merge-store ----
  float bo[8];
#pragma unroll
  for (int n = 0; n < 8; ++n) bo[n] = bout[16 * n + llo];
  float* obase = out + base_off;
#pragma unroll
  for (int r = 0; r < 4; ++r) {
    int t = rowC + r;
    if (t < 49) {
      int wr = t / 7, wc = t - wr * 7;
      float* orow = obase + (wr * 56 + wc) * 128;
#pragma unroll
      for (int n = 0; n < 8; ++n) orow[16 * n + llo] = oc[n][r] + bo[n];
    }
  }
}

extern "C" void kernel_launch(void* const* d_in, const int* in_sizes, int n_in,
                              void* d_out, int out_size, void* d_ws,
                              size_t ws_size, hipStream_t stream) {
  const float* x = (const float*)d_in[0];
  const float* ln_g = (const float*)d_in[1];
  const float* ln_b = (const float*)d_in[2];
  const float* w_qkv = (const float*)d_in[3];
  const float* b_qkv = (const float*)d_in[4];
  const float* w_out = (const float*)d_in[5];
  const float* b_out = (const float*)d_in[6];
  float* out = (float*)d_out;

  u16t* wq_p = (u16t*)d_ws;          // 24*4*64*8 = 49152 bf16 (96 KB)
  u16t* wo_p = wq_p + 24 * 256 * 8;  // 8*4*64*8 = 16384 bf16 (32 KB)

  hipLaunchKernelGGL(pack_weights_kernel, dim3(32), dim3(256), 0, stream,
                     w_qkv, w_out, wq_p, wo_p);
  hipLaunchKernelGGL(win_attn_kernel, dim3(4096), dim3(256), 0, stream, x,
                     ln_g, ln_b, wq_p, b_qkv, wo_p, b_out, out);
}